// Round 10
// baseline (429.877 us; speedup 1.0000x reference)
//
#include <hip/hip_runtime.h>

// B=8, C=256, K=64, H=W=64, HW=4096
using bf16x8 = __attribute__((ext_vector_type(8))) short;
using f16x8  = __attribute__((ext_vector_type(8))) _Float16;
using f32x4  = __attribute__((ext_vector_type(4))) float;

#define DEVI static __device__ __forceinline__

DEVI unsigned short f2bf(float f){
  unsigned u = __builtin_bit_cast(unsigned, f);
  u += 0x7fffu + ((u >> 16) & 1u);
  return (unsigned short)(u >> 16);
}
DEVI float bf2f(unsigned short h){
  unsigned u = ((unsigned)h) << 16;
  return __builtin_bit_cast(float, u);
}
DEVI unsigned short f2h(float f){
  _Float16 h = (_Float16)f;
  return __builtin_bit_cast(unsigned short, h);
}
DEVI f32x4 zf4(){ f32x4 z; z[0]=0.f; z[1]=0.f; z[2]=0.f; z[3]=0.f; return z; }
DEVI unsigned cvtpk(float lo, float hi){
  unsigned r;
  asm("v_cvt_pk_bf16_f32 %0, %1, %2" : "=v"(r) : "v"(lo), "v"(hi));
  return r;
}

// ---------------------------------------------------------------------------
// k_prep: transpose 1x1 weights to [c][k]; pack 3x3 weights to [tau][o][c] bf16
// ---------------------------------------------------------------------------
__global__ __launch_bounds__(256) void k_prep(
    const float* __restrict__ top_w, const float* __restrict__ cen_w,
    const float* __restrict__ bot_w, const float* __restrict__ out_w,
    float* __restrict__ wTt, float* __restrict__ wTc,
    unsigned short* __restrict__ apb, unsigned short* __restrict__ apo){
  int i = blockIdx.x * 256 + threadIdx.x;
  if (i < 64 * 256){
    int c = i >> 6, k = i & 63;
    wTt[i] = top_w[k * 256 + c];
    wTc[i] = cen_w[k * 256 + c];
  }
  if (i < 9 * 256 * 256){
    int tau = i >> 16, oc = i & 65535;   // oc = o*256+c
    apb[i] = f2bf(bot_w[oc * 9 + tau]);
    apo[i] = f2bf(out_w[oc * 9 + tau]);
  }
}

// ---------------------------------------------------------------------------
// k_topcenter: top/center = W[64,256] @ x[256,4096] per batch, fp32 VALU,
// stored transposed [n][k] as fp16 (top pre-scaled by log2 e).
// k-quarter split (16 outputs/thread), XCD-pinned b = bid&7.
// ---------------------------------------------------------------------------
__global__ __launch_bounds__(256) void k_topcenter(
    const float* __restrict__ x,
    const float* __restrict__ wTt, const float* __restrict__ wTc,
    const float* __restrict__ top_b, const float* __restrict__ cen_b,
    unsigned short* __restrict__ tT16, unsigned short* __restrict__ cT16){
  __shared__ float xs[16][256];
  int bid = blockIdx.x;
  int b = bid & 7, z = (bid >> 3) & 1, nt = (bid >> 4) & 15, kq = bid >> 8;
  int t = threadIdx.x;
  int n = nt * 256 + t;
  int k0 = kq * 16;
  const float* wT   = z ? wTc : wTt;
  const float* bias = z ? cen_b : top_b;
  unsigned short* o16 = z ? cT16 : tT16;
  const float scale = z ? 1.0f : 1.4426950408889634f;   // log2(e) folded into top
  const float* xb = x + ((size_t)b << 20);

  float acc[16];
  #pragma unroll
  for (int k = 0; k < 16; k++) acc[k] = 0.f;

  for (int cc = 0; cc < 256; cc += 16){
    __syncthreads();
    #pragma unroll
    for (int r = 0; r < 16; r++)
      xs[r][t] = xb[((size_t)(cc + r) << 12) + nt * 256 + t];
    __syncthreads();
    #pragma unroll
    for (int r = 0; r < 16; r++){
      float xv = xs[r][t];
      const float* wr = wT + (cc + r) * 64 + k0;   // uniform -> scalar loads
      #pragma unroll
      for (int k = 0; k < 16; k++) acc[k] = fmaf(wr[k], xv, acc[k]);
    }
  }
  size_t base = (((size_t)b << 12) + n) * 64 + k0;
  #pragma unroll
  for (int k8 = 0; k8 < 16; k8 += 8){
    bf16x8 v8;
    #pragma unroll
    for (int j = 0; j < 8; j++)
      v8[j] = (short)f2h((acc[k8 + j] + bias[k0 + k8 + j]) * scale);
    *(bf16x8*)(o16 + base + k8) = v8;
  }
}

// ---------------------------------------------------------------------------
// k_transx: channels-first fp32 x -> channels-last bf16 xcl (LDS transpose)
// ---------------------------------------------------------------------------
__global__ __launch_bounds__(256) void k_transx(
    const float* __restrict__ x, unsigned short* __restrict__ ocl){
  __shared__ float tile[32][33];
  int b = blockIdx.z, ct = blockIdx.y, pt = blockIdx.x;
  int tx = threadIdx.x & 31, ty = threadIdx.x >> 5;
  size_t bo = (size_t)b << 20;
  int c0 = ct * 32, p0 = pt * 32;
  #pragma unroll
  for (int q = 0; q < 4; q++){
    int c = c0 + ty + q * 8;
    tile[ty + q * 8][tx] = x[bo + ((size_t)c << 12) + p0 + tx];
  }
  __syncthreads();
  #pragma unroll
  for (int q = 0; q < 4; q++){
    int p = p0 + ty + q * 8;
    ocl[bo + ((size_t)p << 8) + c0 + tx] = f2bf(tile[tx][ty + q * 8]);
  }
}

// ---------------------------------------------------------------------------
// k_transy: y = x + (U0+U1)/Z  (U in bf16) -> channels-last bf16 ycl
// ---------------------------------------------------------------------------
__global__ __launch_bounds__(256) void k_transy(
    const float* __restrict__ x, const unsigned short* __restrict__ U0,
    const unsigned short* __restrict__ U1, const float* __restrict__ Z,
    unsigned short* __restrict__ ocl){
  __shared__ float tile[32][33];
  int b = blockIdx.z, ct = blockIdx.y, pt = blockIdx.x;
  int tx = threadIdx.x & 31, ty = threadIdx.x >> 5;
  size_t bo = (size_t)b << 20;
  int c0 = ct * 32, p0 = pt * 32;
  float invZ = 1.0f / Z[b];
  #pragma unroll
  for (int q = 0; q < 4; q++){
    int c = c0 + ty + q * 8;
    size_t idx = bo + ((size_t)c << 12) + p0 + tx;
    float u = bf2f(U0[idx]);
    if (U1) u += bf2f(U1[idx]);
    tile[ty + q * 8][tx] = fmaf(u, invZ, x[idx]);
  }
  __syncthreads();
  #pragma unroll
  for (int q = 0; q < 4; q++){
    int p = p0 + ty + q * 8;
    ocl[bo + ((size_t)p << 8) + c0 + tx] = f2bf(tile[tx][ty + q * 8]);
  }
}

// ---------------------------------------------------------------------------
// k_conv3: 3x3 SAME conv, halo-row staging reused across 9 taps,
// async-stage: next chunk's global loads issue BEFORE the MFMA section.
// ---------------------------------------------------------------------------
template<int OUTF32>
__global__ __launch_bounds__(256, 4) void k_conv3(
    const unsigned short* __restrict__ incl,
    const unsigned short* __restrict__ ap,
    const float* __restrict__ bias, void* __restrict__ outp){
  __shared__ unsigned short Xs[3][64][72];   // [halo row][w][c-chunk], 144B rows
  int bid = blockIdx.x;
  int b = bid & 7, h = (bid >> 3) & 63, oh = bid >> 9;
  int t = threadIdx.x, wv = t >> 6, l = t & 63, lr = l & 15, g = l >> 4;
  int o0 = oh * 128 + wv * 32;
  const unsigned short* inb = incl + ((size_t)b << 20);

  f32x4 acc[2][4];
  #pragma unroll
  for (int a = 0; a < 2; a++)
    #pragma unroll
    for (int c = 0; c < 4; c++) acc[a][c] = zf4();

  int sw = t >> 2, sco = (t & 3) * 16;
  const bf16x8 zero8 = {0,0,0,0,0,0,0,0};

  bf16x8 st[3][2];
  #pragma unroll
  for (int r = 0; r < 3; r++){
    int h2 = h + r - 1;
    bool v = (unsigned)h2 < 64u;
    #pragma unroll
    for (int u = 0; u < 2; u++)
      st[r][u] = v ? *(const bf16x8*)(inb + (((size_t)(h2 * 64 + sw)) << 8)
                                      + sco + u * 8)
                   : zero8;
  }

  for (int cc = 0; cc < 256; cc += 64){
    __syncthreads();   // A: previous chunk's Xs reads complete
    #pragma unroll
    for (int r = 0; r < 3; r++)
      #pragma unroll
      for (int u = 0; u < 2; u++)
        *(bf16x8*)(&Xs[r][sw][sco + u * 8]) = st[r][u];
    __syncthreads();   // B: Xs visible
    if (cc < 192){
      #pragma unroll
      for (int r = 0; r < 3; r++){
        int h2 = h + r - 1;
        bool v = (unsigned)h2 < 64u;
        #pragma unroll
        for (int u = 0; u < 2; u++)
          st[r][u] = v ? *(const bf16x8*)(inb + (((size_t)(h2 * 64 + sw)) << 8)
                                          + cc + 64 + sco + u * 8)
                       : zero8;
      }
    }
    #pragma unroll
    for (int tau = 0; tau < 9; tau++){
      int dy = tau / 3 - 1, dx = tau % 3 - 1;
      #pragma unroll
      for (int kf = 0; kf < 2; kf++){
        bf16x8 af[2];
        #pragma unroll
        for (int of = 0; of < 2; of++)
          af[of] = *(const bf16x8*)(ap + ((size_t)tau << 16)
                     + ((o0 + of * 16 + lr) << 8) + cc + kf * 32 + 8 * g);
        bf16x8 bv[4];
        #pragma unroll
        for (int pf = 0; pf < 4; pf++){
          int wsrc = pf * 16 + lr + dx;
          bv[pf] = ((unsigned)wsrc < 64u)
                 ? *(const bf16x8*)(&Xs[dy + 1][wsrc][kf * 32 + 8 * g])
                 : zero8;
        }
        #pragma unroll
        for (int of = 0; of < 2; of++)
          #pragma unroll
          for (int pf = 0; pf < 4; pf++)
            acc[of][pf] = __builtin_amdgcn_mfma_f32_16x16x32_bf16(af[of], bv[pf], acc[of][pf], 0, 0, 0);
      }
    }
  }
  #pragma unroll
  for (int of = 0; of < 2; of++){
    int ob = o0 + of * 16 + 4 * g;
    #pragma unroll
    for (int pf = 0; pf < 4; pf++){
      int p = h * 64 + pf * 16 + lr;
      #pragma unroll
      for (int i = 0; i < 4; i++){
        int o = ob + i;
        float v = acc[of][pf][i] + bias[o];
        size_t oi = ((size_t)b << 20) + ((size_t)o << 12) + p;
        if (OUTF32) ((float*)outp)[oi] = v;
        else        ((unsigned short*)outp)[oi] = f2bf(v);
      }
    }
  }
}

// ---------------------------------------------------------------------------
// k_pv v9: fused S(fp16)/exp2/PV. n-tile 64, m-step 32, subtiled LDS
// [m-slot][row][8] (conflict-free), 40KB -> 4 blocks/CU, double-buffered
// 1-barrier pipeline. Per wave per step the 20 MFMAs (4 S + 16 PV) are
// CLUSTERED back-to-back; exp2 + v_cvt_pk_bf16_f32 pack run after the PV
// issue (lockstep-tolerant: non-MFMA serial section shrinks to ~100 cyc).
// ---------------------------------------------------------------------------
__global__ __launch_bounds__(256, 4) void k_pv(
    const unsigned short* __restrict__ tT16, const unsigned short* __restrict__ cT16,
    const unsigned short* __restrict__ xbot,
    unsigned short* __restrict__ U0, unsigned short* __restrict__ U1,
    float* __restrict__ rsum, int nsteps){
  __shared__ unsigned short Xl[2][4][256][8];   // [buf][m-slot][c][8m] 32KB
  __shared__ unsigned short Pl[2][4][64][8];    // [buf][m-slot][n][8m]  8KB
  int bid = blockIdx.x;
  int b = bid & 7, nt = (bid >> 3) & 63, mh = bid >> 9;
  int t = threadIdx.x, wv = t >> 6, l = t & 63, lr = l & 15, g = l >> 4;
  int n0 = nt * 64;
  const unsigned short* xbb = xbot + ((size_t)b << 20);
  unsigned short* Ub = mh ? U1 : U0;

  // cen fp16 frags: n = n0 + (wv>>1)*32 + nf*16 + lr, k = kf*32 + 8g
  f16x8 ch[2][2];
  #pragma unroll
  for (int kf = 0; kf < 2; kf++)
    #pragma unroll
    for (int nf = 0; nf < 2; nf++)
      ch[kf][nf] = *(const f16x8*)(cT16
          + (((size_t)b << 12) + n0 + (wv >> 1) * 32 + nf * 16 + lr) * 64
          + kf * 32 + 8 * g);

  f32x4 acc[4][4];
  #pragma unroll
  for (int a = 0; a < 4; a++)
    #pragma unroll
    for (int c = 0; c < 4; c++) acc[a][c] = zf4();
  float racc = 0.f;

  // S A-frags: row m = mh*2048 + ms*32 + (wv&1)*16 + lr
  const unsigned short* tb = tT16
      + (((size_t)b << 12) + (size_t)mh * 2048 + (wv & 1) * 16 + lr) * 64 + 8 * g;

  // Xl staging: instr j -> slot j (m-chunk j*8), lane l -> c = wv*64 + l
  const unsigned short* gsrc = xbb + ((size_t)(wv * 64 + l) << 12)
                             + (size_t)mh * 2048;

  f16x8 a0 = *(const f16x8*)(tb);
  f16x8 a1 = *(const f16x8*)(tb + 32);
  int mt2 = (wv & 1) * 2 + (g >> 1);

  // --- prologue: stage step 0, compute S(0), write Pl[0]
  {
    #pragma unroll
    for (int j = 0; j < 4; j++)
      __builtin_amdgcn_global_load_lds(
          (const __attribute__((address_space(1))) void*)(gsrc + j * 8),
          (__attribute__((address_space(3))) void*)(&Xl[0][j][wv * 64][0]),
          16, 0, 0);
    f32x4 sa[2];
    sa[0] = zf4(); sa[1] = zf4();
    #pragma unroll
    for (int nf = 0; nf < 2; nf++)
      sa[nf] = __builtin_amdgcn_mfma_f32_16x16x32_f16(a0, ch[0][nf], sa[nf], 0, 0, 0);
    #pragma unroll
    for (int nf = 0; nf < 2; nf++)
      sa[nf] = __builtin_amdgcn_mfma_f32_16x16x32_f16(a1, ch[1][nf], sa[nf], 0, 0, 0);
    a0 = *(const f16x8*)(tb + 2048);
    a1 = *(const f16x8*)(tb + 2048 + 32);
    #pragma unroll
    for (int nf = 0; nf < 2; nf++){
      float e0 = __builtin_amdgcn_exp2f(sa[nf][0]);
      float e1 = __builtin_amdgcn_exp2f(sa[nf][1]);
      float e2 = __builtin_amdgcn_exp2f(sa[nf][2]);
      float e3 = __builtin_amdgcn_exp2f(sa[nf][3]);
      racc += (e0 + e1) + (e2 + e3);
      int n = (wv >> 1) * 32 + nf * 16 + lr;
      unsigned* pp = (unsigned*)(&Pl[0][mt2][n][(g & 1) * 4]);
      pp[0] = cvtpk(e0, e1);
      pp[1] = cvtpk(e2, e3);
    }
    __syncthreads();
  }

  for (int ms = 0; ms < nsteps; ms++){
    int cur = ms & 1, nxt = cur ^ 1;
    bool more = (ms + 1 < nsteps);
    f32x4 sa[2];
    sa[0] = zf4(); sa[1] = zf4();
    if (more){
      // stage Xl[nxt]: in flight across the whole MFMA cluster
      #pragma unroll
      for (int j = 0; j < 4; j++)
        __builtin_amdgcn_global_load_lds(
            (const __attribute__((address_space(1))) void*)(gsrc + (ms + 1) * 32 + j * 8),
            (__attribute__((address_space(3))) void*)(&Xl[nxt][j][wv * 64][0]),
            16, 0, 0);
      // S MFMAs for step ms+1 (head of the MFMA cluster)
      #pragma unroll
      for (int nf = 0; nf < 2; nf++)
        sa[nf] = __builtin_amdgcn_mfma_f32_16x16x32_f16(a0, ch[0][nf], sa[nf], 0, 0, 0);
      #pragma unroll
      for (int nf = 0; nf < 2; nf++)
        sa[nf] = __builtin_amdgcn_mfma_f32_16x16x32_f16(a1, ch[1][nf], sa[nf], 0, 0, 0);
      if (ms + 2 < nsteps){
        a0 = *(const f16x8*)(tb + (size_t)(ms + 2) * 2048);
        a1 = *(const f16x8*)(tb + (size_t)(ms + 2) * 2048 + 32);
      }
    }
    // PV MFMAs (bulk of the cluster) on buffers[cur]
    {
      bf16x8 pa[4];
      #pragma unroll
      for (int nf = 0; nf < 4; nf++)
        pa[nf] = *(const bf16x8*)(&Pl[cur][g][nf * 16 + lr][0]);
      #pragma unroll
      for (int cf = 0; cf < 4; cf++){
        bf16x8 bx = *(const bf16x8*)(&Xl[cur][g][wv * 64 + cf * 16 + lr][0]);
        #pragma unroll
        for (int nf = 0; nf < 4; nf++)
          acc[nf][cf] = __builtin_amdgcn_mfma_f32_16x16x32_bf16(pa[nf], bx, acc[nf][cf], 0, 0, 0);
      }
    }
    // exp2 + cvt_pk pack (short VALU tail; overlaps MFMA latency) -> Pl[nxt]
    if (more){
      #pragma unroll
      for (int nf = 0; nf < 2; nf++){
        float e0 = __builtin_amdgcn_exp2f(sa[nf][0]);
        float e1 = __builtin_amdgcn_exp2f(sa[nf][1]);
        float e2 = __builtin_amdgcn_exp2f(sa[nf][2]);
        float e3 = __builtin_amdgcn_exp2f(sa[nf][3]);
        racc += (e0 + e1) + (e2 + e3);
        int n = (wv >> 1) * 32 + nf * 16 + lr;
        unsigned* pp = (unsigned*)(&Pl[nxt][mt2][n][(g & 1) * 4]);
        pp[0] = cvtpk(e0, e1);
        pp[1] = cvtpk(e2, e3);
      }
    }
    __syncthreads();           // one barrier/step
  }

  // --- write unnormalized U partial in bf16 (flat n*256+c == reshape)
  #pragma unroll
  for (int nf = 0; nf < 4; nf++)
    #pragma unroll
    for (int cf = 0; cf < 4; cf++)
      #pragma unroll
      for (int i = 0; i < 4; i++){
        int n = n0 + nf * 16 + 4 * g + i;
        int c = wv * 64 + cf * 16 + lr;
        __builtin_nontemporal_store(f2bf(acc[nf][cf][i]),
            &Ub[((size_t)b << 20) + ((size_t)n << 8) + c]);
      }
  // --- Z partial: wave scalar
  racc += __shfl_xor(racc, 1);
  racc += __shfl_xor(racc, 2);
  racc += __shfl_xor(racc, 4);
  racc += __shfl_xor(racc, 8);
  racc += __shfl_xor(racc, 16);
  racc += __shfl_xor(racc, 32);
  if (l == 0) rsum[(size_t)bid * 4 + wv] = racc;
}

// ---------------------------------------------------------------------------
// k_rsum: Z[b] = sum of this batch's wave partials.
// rsum slot layout: bid*4+wv, bid = b + 8*j -> slot s: j = s>>2, wv = s&3.
// ---------------------------------------------------------------------------
__global__ __launch_bounds__(256) void k_rsum(const float* __restrict__ r,
                                              float* __restrict__ Z, int total){
  __shared__ float red[256];
  int b = blockIdx.x, t = threadIdx.x;
  float s = 0.f;
  for (int s2 = t; s2 < total; s2 += 256)
    s += r[(size_t)(b + 8 * (s2 >> 2)) * 4 + (s2 & 3)];
  red[t] = s;
  __syncthreads();
  for (int o = 128; o > 0; o >>= 1){
    if (t < o) red[t] += red[t + o];
    __syncthreads();
  }
  if (t == 0) Z[b] = red[0];
}

// ---------------------------------------------------------------------------
extern "C" void kernel_launch(void* const* d_in, const int* in_sizes, int n_in,
                              void* d_out, int out_size, void* d_ws, size_t ws_size,
                              hipStream_t stream) {
  const float* x     = (const float*)d_in[0];
  const float* top_w = (const float*)d_in[1];
  const float* top_b = (const float*)d_in[2];
  const float* cen_w = (const float*)d_in[3];
  const float* cen_b = (const float*)d_in[4];
  const float* bot_w = (const float*)d_in[5];
  const float* bot_b = (const float*)d_in[6];
  const float* out_w = (const float*)d_in[7];
  const float* out_b = (const float*)d_in[8];
  float* out = (float*)d_out;

  constexpr size_t MB = 1ull << 20;
  int msplit = (ws_size >= 80 * MB) ? 2 : 1;

  char* p = (char*)d_ws;
  unsigned short* U0 = (unsigned short*)p;     p += 16 * MB;   // bf16 U partial
  unsigned short* U1 = nullptr;
  if (msplit == 2){ U1 = (unsigned short*)p;   p += 16 * MB; }
  unsigned short* tT16 = (unsigned short*)p;   p += 4 * MB;
  unsigned short* cT16 = (unsigned short*)p;   p += 4 * MB;
  unsigned short* xbot = (unsigned short*)p;   p += 16 * MB;
  unsigned short* xcl  = (unsigned short*)p;   p += 16 * MB;  // reused as ycl
  float* wTt = (float*)p;                      p += 65536;
  float* wTc = (float*)p;                      p += 65536;
  unsigned short* apb = (unsigned short*)p;    p += 1179648;
  unsigned short* apo = (unsigned short*)p;    p += 1179648;
  float* r = (float*)p;                        p += 65536;
  float* Z = (float*)p;

  int grid_pv = 8 * 64 * msplit;          // (b, nt:64, mh)
  int nsteps  = (4096 / msplit) / 32;     // 32-m steps per block
  int slots   = (grid_pv / 8) * 4;        // rsum slots per batch

  // 1. weight prep
  k_prep<<<2304, 256, 0, stream>>>(top_w, cen_w, bot_w, out_w, wTt, wTc, apb, apo);
  // 2. top/center 1x1 convs -> fp16 transposed (k-quarter split, XCD-pinned)
  k_topcenter<<<dim3(1024), 256, 0, stream>>>(x, wTt, wTc, top_b, cen_b,
                                              tT16, cT16);
  // 3. x -> channels-last bf16 (LDS transpose, coalesced)
  k_transx<<<dim3(128, 8, 8), 256, 0, stream>>>(x, xcl);
  // 4. bottom 3x3 conv -> x_bottom bf16 [b][c][p]
  k_conv3<0><<<dim3(1024), 256, 0, stream>>>(xcl, apb, bot_b, (void*)xbot);
  // 5. fused S/exp/PV -> bf16 U partials + wave partials for Z
  k_pv<<<dim3(grid_pv), 256, 0, stream>>>(tT16, cT16, xbot, U0,
                                          msplit == 2 ? U1 : U0, r, nsteps);
  // 6. Z per batch
  k_rsum<<<8, 256, 0, stream>>>(r, Z, slots);
  // 7. y = x + (U0+U1)/Z -> ycl bf16
  k_transy<<<dim3(128, 8, 8), 256, 0, stream>>>(x, U0, U1, Z, xcl);
  // 8. final 3x3 conv -> d_out fp32
  k_conv3<1><<<dim3(1024), 256, 0, stream>>>(xcl, apo, out_b, (void*)out);
}

// Round 11
// 304.425 us; speedup vs baseline: 1.4121x; 1.4121x over previous
//
#include <hip/hip_runtime.h>

// B=8, C=256, K=64, H=W=64, HW=4096
using bf16x8 = __attribute__((ext_vector_type(8))) short;
using f16x8  = __attribute__((ext_vector_type(8))) _Float16;
using f32x4  = __attribute__((ext_vector_type(4))) float;

#define DEVI static __device__ __forceinline__

DEVI unsigned short f2bf(float f){
  unsigned u = __builtin_bit_cast(unsigned, f);
  u += 0x7fffu + ((u >> 16) & 1u);
  return (unsigned short)(u >> 16);
}
DEVI float bf2f(unsigned short h){
  unsigned u = ((unsigned)h) << 16;
  return __builtin_bit_cast(float, u);
}
DEVI unsigned short f2h(float f){
  _Float16 h = (_Float16)f;
  return __builtin_bit_cast(unsigned short, h);
}
DEVI f32x4 zf4(){ f32x4 z; z[0]=0.f; z[1]=0.f; z[2]=0.f; z[3]=0.f; return z; }
DEVI unsigned cvtpk(float lo, float hi){
  unsigned r;
  asm("v_cvt_pk_bf16_f32 %0, %1, %2" : "=v"(r) : "v"(lo), "v"(hi));
  return r;
}

// ---------------------------------------------------------------------------
// k_prep: transpose 1x1 weights to [c][k]; pack 3x3 weights to [tau][o][c] bf16
// ---------------------------------------------------------------------------
__global__ __launch_bounds__(256) void k_prep(
    const float* __restrict__ top_w, const float* __restrict__ cen_w,
    const float* __restrict__ bot_w, const float* __restrict__ out_w,
    float* __restrict__ wTt, float* __restrict__ wTc,
    unsigned short* __restrict__ apb, unsigned short* __restrict__ apo){
  int i = blockIdx.x * 256 + threadIdx.x;
  if (i < 64 * 256){
    int c = i >> 6, k = i & 63;
    wTt[i] = top_w[k * 256 + c];
    wTc[i] = cen_w[k * 256 + c];
  }
  if (i < 9 * 256 * 256){
    int tau = i >> 16, oc = i & 65535;   // oc = o*256+c
    apb[i] = f2bf(bot_w[oc * 9 + tau]);
    apo[i] = f2bf(out_w[oc * 9 + tau]);
  }
}

// ---------------------------------------------------------------------------
// k_topcenter: top/center = W[64,256] @ x[256,4096] per batch, fp32 VALU,
// stored transposed [n][k] as fp16 (top pre-scaled by log2 e).
// k-quarter split (16 outputs/thread), XCD-pinned b = bid&7.
// ---------------------------------------------------------------------------
__global__ __launch_bounds__(256) void k_topcenter(
    const float* __restrict__ x,
    const float* __restrict__ wTt, const float* __restrict__ wTc,
    const float* __restrict__ top_b, const float* __restrict__ cen_b,
    unsigned short* __restrict__ tT16, unsigned short* __restrict__ cT16){
  __shared__ float xs[16][256];
  int bid = blockIdx.x;
  int b = bid & 7, z = (bid >> 3) & 1, nt = (bid >> 4) & 15, kq = bid >> 8;
  int t = threadIdx.x;
  int n = nt * 256 + t;
  int k0 = kq * 16;
  const float* wT   = z ? wTc : wTt;
  const float* bias = z ? cen_b : top_b;
  unsigned short* o16 = z ? cT16 : tT16;
  const float scale = z ? 1.0f : 1.4426950408889634f;   // log2(e) folded into top
  const float* xb = x + ((size_t)b << 20);

  float acc[16];
  #pragma unroll
  for (int k = 0; k < 16; k++) acc[k] = 0.f;

  for (int cc = 0; cc < 256; cc += 16){
    __syncthreads();
    #pragma unroll
    for (int r = 0; r < 16; r++)
      xs[r][t] = xb[((size_t)(cc + r) << 12) + nt * 256 + t];
    __syncthreads();
    #pragma unroll
    for (int r = 0; r < 16; r++){
      float xv = xs[r][t];
      const float* wr = wT + (cc + r) * 64 + k0;   // uniform -> scalar loads
      #pragma unroll
      for (int k = 0; k < 16; k++) acc[k] = fmaf(wr[k], xv, acc[k]);
    }
  }
  size_t base = (((size_t)b << 12) + n) * 64 + k0;
  #pragma unroll
  for (int k8 = 0; k8 < 16; k8 += 8){
    bf16x8 v8;
    #pragma unroll
    for (int j = 0; j < 8; j++)
      v8[j] = (short)f2h((acc[k8 + j] + bias[k0 + k8 + j]) * scale);
    *(bf16x8*)(o16 + base + k8) = v8;
  }
}

// ---------------------------------------------------------------------------
// k_transx: channels-first fp32 x -> channels-last bf16 xcl (LDS transpose)
// ---------------------------------------------------------------------------
__global__ __launch_bounds__(256) void k_transx(
    const float* __restrict__ x, unsigned short* __restrict__ ocl){
  __shared__ float tile[32][33];
  int b = blockIdx.z, ct = blockIdx.y, pt = blockIdx.x;
  int tx = threadIdx.x & 31, ty = threadIdx.x >> 5;
  size_t bo = (size_t)b << 20;
  int c0 = ct * 32, p0 = pt * 32;
  #pragma unroll
  for (int q = 0; q < 4; q++){
    int c = c0 + ty + q * 8;
    tile[ty + q * 8][tx] = x[bo + ((size_t)c << 12) + p0 + tx];
  }
  __syncthreads();
  #pragma unroll
  for (int q = 0; q < 4; q++){
    int p = p0 + ty + q * 8;
    ocl[bo + ((size_t)p << 8) + c0 + tx] = f2bf(tile[tx][ty + q * 8]);
  }
}

// ---------------------------------------------------------------------------
// k_transy: y = x + (U0+U1)/Z  (U in bf16) -> channels-last bf16 ycl
// ---------------------------------------------------------------------------
__global__ __launch_bounds__(256) void k_transy(
    const float* __restrict__ x, const unsigned short* __restrict__ U0,
    const unsigned short* __restrict__ U1, const float* __restrict__ Z,
    unsigned short* __restrict__ ocl){
  __shared__ float tile[32][33];
  int b = blockIdx.z, ct = blockIdx.y, pt = blockIdx.x;
  int tx = threadIdx.x & 31, ty = threadIdx.x >> 5;
  size_t bo = (size_t)b << 20;
  int c0 = ct * 32, p0 = pt * 32;
  float invZ = 1.0f / Z[b];
  #pragma unroll
  for (int q = 0; q < 4; q++){
    int c = c0 + ty + q * 8;
    size_t idx = bo + ((size_t)c << 12) + p0 + tx;
    float u = bf2f(U0[idx]);
    if (U1) u += bf2f(U1[idx]);
    tile[ty + q * 8][tx] = fmaf(u, invZ, x[idx]);
  }
  __syncthreads();
  #pragma unroll
  for (int q = 0; q < 4; q++){
    int p = p0 + ty + q * 8;
    ocl[bo + ((size_t)p << 8) + c0 + tx] = f2bf(tile[tx][ty + q * 8]);
  }
}

// ---------------------------------------------------------------------------
// k_conv3: 3x3 SAME conv, halo-row staging reused across 9 taps.
// OUTF32=1: normal orientation (D rows=o, cols=p), fp32 out [b][o][p].
// OUTF32=0: FLIPPED operands (mfma(xtile, weights) -> D rows=p, cols=o) so
// the epilogue emits xbot_t[b][mc=p>>3][o][p&7] with 8B-contiguous stores
// (16 lanes = 256B contiguous) -- the pre-subtiled layout k_pv stages from.
// ---------------------------------------------------------------------------
template<int OUTF32>
__global__ __launch_bounds__(256, 4) void k_conv3(
    const unsigned short* __restrict__ incl,
    const unsigned short* __restrict__ ap,
    const float* __restrict__ bias, void* __restrict__ outp){
  __shared__ unsigned short Xs[3][64][72];   // [halo row][w][c-chunk], 144B rows
  int bid = blockIdx.x;
  int b = bid & 7, h = (bid >> 3) & 63, oh = bid >> 9;
  int t = threadIdx.x, wv = t >> 6, l = t & 63, lr = l & 15, g = l >> 4;
  int o0 = oh * 128 + wv * 32;
  const unsigned short* inb = incl + ((size_t)b << 20);

  f32x4 acc[2][4];
  #pragma unroll
  for (int a = 0; a < 2; a++)
    #pragma unroll
    for (int c = 0; c < 4; c++) acc[a][c] = zf4();

  int sw = t >> 2, sco = (t & 3) * 16;
  const bf16x8 zero8 = {0,0,0,0,0,0,0,0};

  bf16x8 st[3][2];
  #pragma unroll
  for (int r = 0; r < 3; r++){
    int h2 = h + r - 1;
    bool v = (unsigned)h2 < 64u;
    #pragma unroll
    for (int u = 0; u < 2; u++)
      st[r][u] = v ? *(const bf16x8*)(inb + (((size_t)(h2 * 64 + sw)) << 8)
                                      + sco + u * 8)
                   : zero8;
  }

  for (int cc = 0; cc < 256; cc += 64){
    __syncthreads();   // A: previous chunk's Xs reads complete
    #pragma unroll
    for (int r = 0; r < 3; r++)
      #pragma unroll
      for (int u = 0; u < 2; u++)
        *(bf16x8*)(&Xs[r][sw][sco + u * 8]) = st[r][u];
    __syncthreads();   // B: Xs visible
    if (cc < 192){
      #pragma unroll
      for (int r = 0; r < 3; r++){
        int h2 = h + r - 1;
        bool v = (unsigned)h2 < 64u;
        #pragma unroll
        for (int u = 0; u < 2; u++)
          st[r][u] = v ? *(const bf16x8*)(inb + (((size_t)(h2 * 64 + sw)) << 8)
                                          + cc + 64 + sco + u * 8)
                       : zero8;
      }
    }
    #pragma unroll
    for (int tau = 0; tau < 9; tau++){
      int dy = tau / 3 - 1, dx = tau % 3 - 1;
      #pragma unroll
      for (int kf = 0; kf < 2; kf++){
        bf16x8 af[2];
        #pragma unroll
        for (int of = 0; of < 2; of++)
          af[of] = *(const bf16x8*)(ap + ((size_t)tau << 16)
                     + ((o0 + of * 16 + lr) << 8) + cc + kf * 32 + 8 * g);
        bf16x8 bv[4];
        #pragma unroll
        for (int pf = 0; pf < 4; pf++){
          int wsrc = pf * 16 + lr + dx;
          bv[pf] = ((unsigned)wsrc < 64u)
                 ? *(const bf16x8*)(&Xs[dy + 1][wsrc][kf * 32 + 8 * g])
                 : zero8;
        }
        #pragma unroll
        for (int of = 0; of < 2; of++)
          #pragma unroll
          for (int pf = 0; pf < 4; pf++){
            if (OUTF32)   // D rows=o, cols=p
              acc[of][pf] = __builtin_amdgcn_mfma_f32_16x16x32_bf16(af[of], bv[pf], acc[of][pf], 0, 0, 0);
            else          // flipped: D rows=p, cols=o
              acc[of][pf] = __builtin_amdgcn_mfma_f32_16x16x32_bf16(bv[pf], af[of], acc[of][pf], 0, 0, 0);
          }
      }
    }
  }
  if (OUTF32){
    #pragma unroll
    for (int of = 0; of < 2; of++){
      int ob = o0 + of * 16 + 4 * g;
      #pragma unroll
      for (int pf = 0; pf < 4; pf++){
        int p = h * 64 + pf * 16 + lr;
        #pragma unroll
        for (int i = 0; i < 4; i++){
          int o = ob + i;
          ((float*)outp)[((size_t)b << 20) + ((size_t)o << 12) + p]
              = acc[of][pf][i] + bias[o];
        }
      }
    }
  } else {
    // xbot_t[b][mc][o][8], one 8B store per (of,pf)
    unsigned short* xbt = (unsigned short*)outp;
    #pragma unroll
    for (int of = 0; of < 2; of++){
      int o = o0 + of * 16 + lr;
      float bo_ = bias[o];
      #pragma unroll
      for (int pf = 0; pf < 4; pf++){
        int mc = h * 8 + pf * 2 + (g >> 1);
        unsigned lo = cvtpk(acc[of][pf][0] + bo_, acc[of][pf][1] + bo_);
        unsigned hi = cvtpk(acc[of][pf][2] + bo_, acc[of][pf][3] + bo_);
        unsigned* dst = (unsigned*)(xbt
            + ((((size_t)b * 512 + mc) * 256 + o) * 8 + 4 * (g & 1)));
        dst[0] = lo;
        dst[1] = hi;
      }
    }
  }
}

// ---------------------------------------------------------------------------
// k_pv v10: fused S(fp16)/exp2/PV. n-tile 128, subtiled LDS [slot][row][8]
// (conflict-free), COALESCED staging from pre-subtiled xbot_t (1KB contiguous
// per global_load_lds), clustered MFMAs (8 S + 32 PV back-to-back), exp2 +
// v_cvt_pk_bf16_f32 tail after PV issue. 48KB LDS, (256,2), dbuf, 1 barrier.
// ---------------------------------------------------------------------------
__global__ __launch_bounds__(256, 2) void k_pv(
    const unsigned short* __restrict__ tT16, const unsigned short* __restrict__ cT16,
    const unsigned short* __restrict__ xbt,
    unsigned short* __restrict__ U0, unsigned short* __restrict__ U1,
    float* __restrict__ rsum, int nsteps){
  __shared__ unsigned short Xl[2][4][256][8];   // [buf][m-slot][c][8m] 32KB
  __shared__ unsigned short Pl[2][4][128][8];   // [buf][m-slot][n][8m] 16KB
  int bid = blockIdx.x;
  int b = bid & 7, nt = (bid >> 3) & 31, mh = bid >> 8;
  int t = threadIdx.x, wv = t >> 6, l = t & 63, lr = l & 15, g = l >> 4;
  int n0 = nt * 128;
  unsigned short* Ub = mh ? U1 : U0;

  // cen fp16 frags: n = n0 + (wv>>1)*64 + nf*16 + lr, k = kf*32 + 8g
  f16x8 ch[2][4];
  #pragma unroll
  for (int kf = 0; kf < 2; kf++)
    #pragma unroll
    for (int nf = 0; nf < 4; nf++)
      ch[kf][nf] = *(const f16x8*)(cT16
          + (((size_t)b << 12) + n0 + (wv >> 1) * 64 + nf * 16 + lr) * 64
          + kf * 32 + 8 * g);

  f32x4 acc[8][4];
  #pragma unroll
  for (int a = 0; a < 8; a++)
    #pragma unroll
    for (int c = 0; c < 4; c++) acc[a][c] = zf4();
  float racc = 0.f;

  // S A-frags: row m = mh*2048 + ms*32 + (wv&1)*16 + lr
  const unsigned short* tb = tT16
      + (((size_t)b << 12) + (size_t)mh * 2048 + (wv & 1) * 16 + lr) * 64 + 8 * g;

  // staging: instr j covers c = wv*64..+63, m-chunk (mh*256 + ms*4 + j).
  // source is lane-contiguous (1KB per instr); LDS dest linear.
  const unsigned short* gsrc = xbt
      + (((size_t)b * 512 + (size_t)mh * 256) * 256 + wv * 64 + l) * 8;

  int mt2 = (wv & 1) * 2 + (g >> 1);
  f16x8 a0 = *(const f16x8*)(tb);
  f16x8 a1 = *(const f16x8*)(tb + 32);

  // --- prologue: stage step 0, S(0), Pl[0]
  {
    #pragma unroll
    for (int j = 0; j < 4; j++)
      __builtin_amdgcn_global_load_lds(
          (const __attribute__((address_space(1))) void*)(gsrc + (size_t)j * 2048),
          (__attribute__((address_space(3))) void*)(&Xl[0][j][wv * 64][0]),
          16, 0, 0);
    f32x4 sa[4];
    #pragma unroll
    for (int nf = 0; nf < 4; nf++) sa[nf] = zf4();
    #pragma unroll
    for (int nf = 0; nf < 4; nf++)
      sa[nf] = __builtin_amdgcn_mfma_f32_16x16x32_f16(a0, ch[0][nf], sa[nf], 0, 0, 0);
    #pragma unroll
    for (int nf = 0; nf < 4; nf++)
      sa[nf] = __builtin_amdgcn_mfma_f32_16x16x32_f16(a1, ch[1][nf], sa[nf], 0, 0, 0);
    a0 = *(const f16x8*)(tb + 2048);
    a1 = *(const f16x8*)(tb + 2048 + 32);
    #pragma unroll
    for (int nf = 0; nf < 4; nf++){
      float e0 = __builtin_amdgcn_exp2f(sa[nf][0]);
      float e1 = __builtin_amdgcn_exp2f(sa[nf][1]);
      float e2 = __builtin_amdgcn_exp2f(sa[nf][2]);
      float e3 = __builtin_amdgcn_exp2f(sa[nf][3]);
      racc += (e0 + e1) + (e2 + e3);
      int n = (wv >> 1) * 64 + nf * 16 + lr;
      unsigned* pp = (unsigned*)(&Pl[0][mt2][n][(g & 1) * 4]);
      pp[0] = cvtpk(e0, e1);
      pp[1] = cvtpk(e2, e3);
    }
    __syncthreads();
  }

  for (int ms = 0; ms < nsteps; ms++){
    int cur = ms & 1, nxt = cur ^ 1;
    bool more = (ms + 1 < nsteps);
    f32x4 sa[4];
    #pragma unroll
    for (int nf = 0; nf < 4; nf++) sa[nf] = zf4();
    if (more){
      // stage Xl[nxt]: coalesced, in flight across the whole MFMA cluster
      #pragma unroll
      for (int j = 0; j < 4; j++)
        __builtin_amdgcn_global_load_lds(
            (const __attribute__((address_space(1))) void*)(gsrc + (size_t)((ms + 1) * 4 + j) * 2048),
            (__attribute__((address_space(3))) void*)(&Xl[nxt][j][wv * 64][0]),
            16, 0, 0);
      // S MFMAs for step ms+1 (head of the cluster)
      #pragma unroll
      for (int nf = 0; nf < 4; nf++)
        sa[nf] = __builtin_amdgcn_mfma_f32_16x16x32_f16(a0, ch[0][nf], sa[nf], 0, 0, 0);
      #pragma unroll
      for (int nf = 0; nf < 4; nf++)
        sa[nf] = __builtin_amdgcn_mfma_f32_16x16x32_f16(a1, ch[1][nf], sa[nf], 0, 0, 0);
      if (ms + 2 < nsteps){
        a0 = *(const f16x8*)(tb + (size_t)(ms + 2) * 2048);
        a1 = *(const f16x8*)(tb + (size_t)(ms + 2) * 2048 + 32);
      }
    }
    // PV (32 MFMA) on buffers[cur]
    {
      bf16x8 pa[8];
      #pragma unroll
      for (int nf = 0; nf < 8; nf++)
        pa[nf] = *(const bf16x8*)(&Pl[cur][g][nf * 16 + lr][0]);
      #pragma unroll
      for (int cf = 0; cf < 4; cf++){
        bf16x8 bx = *(const bf16x8*)(&Xl[cur][g][wv * 64 + cf * 16 + lr][0]);
        #pragma unroll
        for (int nf = 0; nf < 8; nf++)
          acc[nf][cf] = __builtin_amdgcn_mfma_f32_16x16x32_bf16(pa[nf], bx, acc[nf][cf], 0, 0, 0);
      }
    }
    // exp2 + cvt_pk tail (overlaps MFMA drain) -> Pl[nxt]
    if (more){
      #pragma unroll
      for (int nf = 0; nf < 4; nf++){
        float e0 = __builtin_amdgcn_exp2f(sa[nf][0]);
        float e1 = __builtin_amdgcn_exp2f(sa[nf][1]);
        float e2 = __builtin_amdgcn_exp2f(sa[nf][2]);
        float e3 = __builtin_amdgcn_exp2f(sa[nf][3]);
        racc += (e0 + e1) + (e2 + e3);
        int n = (wv >> 1) * 64 + nf * 16 + lr;
        unsigned* pp = (unsigned*)(&Pl[nxt][mt2][n][(g & 1) * 4]);
        pp[0] = cvtpk(e0, e1);
        pp[1] = cvtpk(e2, e3);
      }
    }
    __syncthreads();           // one barrier/step
  }

  // --- write unnormalized U partial in bf16 (flat n*256+c == reshape)
  #pragma unroll
  for (int nf = 0; nf < 8; nf++)
    #pragma unroll
    for (int cf = 0; cf < 4; cf++)
      #pragma unroll
      for (int i = 0; i < 4; i++){
        int n = n0 + nf * 16 + 4 * g + i;
        int c = wv * 64 + cf * 16 + lr;
        __builtin_nontemporal_store(f2bf(acc[nf][cf][i]),
            &Ub[((size_t)b << 20) + ((size_t)n << 8) + c]);
      }
  // --- Z partial: wave scalar
  racc += __shfl_xor(racc, 1);
  racc += __shfl_xor(racc, 2);
  racc += __shfl_xor(racc, 4);
  racc += __shfl_xor(racc, 8);
  racc += __shfl_xor(racc, 16);
  racc += __shfl_xor(racc, 32);
  if (l == 0) rsum[(size_t)bid * 4 + wv] = racc;
}

// ---------------------------------------------------------------------------
// k_rsum: Z[b] = sum of this batch's wave partials.
// ---------------------------------------------------------------------------
__global__ __launch_bounds__(256) void k_rsum(const float* __restrict__ r,
                                              float* __restrict__ Z, int total){
  __shared__ float red[256];
  int b = blockIdx.x, t = threadIdx.x;
  float s = 0.f;
  for (int s2 = t; s2 < total; s2 += 256)
    s += r[(size_t)(b + 8 * (s2 >> 2)) * 4 + (s2 & 3)];
  red[t] = s;
  __syncthreads();
  for (int o = 128; o > 0; o >>= 1){
    if (t < o) red[t] += red[t + o];
    __syncthreads();
  }
  if (t == 0) Z[b] = red[0];
}

// ---------------------------------------------------------------------------
extern "C" void kernel_launch(void* const* d_in, const int* in_sizes, int n_in,
                              void* d_out, int out_size, void* d_ws, size_t ws_size,
                              hipStream_t stream) {
  const float* x     = (const float*)d_in[0];
  const float* top_w = (const float*)d_in[1];
  const float* top_b = (const float*)d_in[2];
  const float* cen_w = (const float*)d_in[3];
  const float* cen_b = (const float*)d_in[4];
  const float* bot_w = (const float*)d_in[5];
  const float* bot_b = (const float*)d_in[6];
  const float* out_w = (const float*)d_in[7];
  const float* out_b = (const float*)d_in[8];
  float* out = (float*)d_out;

  constexpr size_t MB = 1ull << 20;
  int msplit = (ws_size >= 80 * MB) ? 2 : 1;

  char* p = (char*)d_ws;
  unsigned short* U0 = (unsigned short*)p;     p += 16 * MB;   // bf16 U partial
  unsigned short* U1 = nullptr;
  if (msplit == 2){ U1 = (unsigned short*)p;   p += 16 * MB; }
  unsigned short* tT16 = (unsigned short*)p;   p += 4 * MB;
  unsigned short* cT16 = (unsigned short*)p;   p += 4 * MB;
  unsigned short* xbt  = (unsigned short*)p;   p += 16 * MB;   // xbot_t subtiled
  unsigned short* xcl  = (unsigned short*)p;   p += 16 * MB;   // reused as ycl
  float* wTt = (float*)p;                      p += 65536;
  float* wTc = (float*)p;                      p += 65536;
  unsigned short* apb = (unsigned short*)p;    p += 1179648;
  unsigned short* apo = (unsigned short*)p;    p += 1179648;
  float* r = (float*)p;                        p += 65536;
  float* Z = (float*)p;

  int grid_pv = 8 * 32 * msplit;          // (b, nt:32, mh)
  int nsteps  = (4096 / msplit) / 32;     // 32-m steps per block
  int slots   = (grid_pv / 8) * 4;        // rsum slots per batch

  // 1. weight prep
  k_prep<<<2304, 256, 0, stream>>>(top_w, cen_w, bot_w, out_w, wTt, wTc, apb, apo);
  // 2. top/center 1x1 convs -> fp16 transposed (k-quarter split, XCD-pinned)
  k_topcenter<<<dim3(1024), 256, 0, stream>>>(x, wTt, wTc, top_b, cen_b,
                                              tT16, cT16);
  // 3. x -> channels-last bf16 (LDS transpose, coalesced)
  k_transx<<<dim3(128, 8, 8), 256, 0, stream>>>(x, xcl);
  // 4. bottom 3x3 conv -> xbot_t[b][mc][o][8] (flipped MFMA, coalesced 8B)
  k_conv3<0><<<dim3(1024), 256, 0, stream>>>(xcl, apb, bot_b, (void*)xbt);
  // 5. fused S/exp/PV -> bf16 U partials + wave partials for Z
  k_pv<<<dim3(grid_pv), 256, 0, stream>>>(tT16, cT16, xbt, U0,
                                          msplit == 2 ? U1 : U0, r, nsteps);
  // 6. Z per batch
  k_rsum<<<8, 256, 0, stream>>>(r, Z, slots);
  // 7. y = x + (U0+U1)/Z -> ycl bf16
  k_transy<<<dim3(128, 8, 8), 256, 0, stream>>>(x, U0, U1, Z, xcl);
  // 8. final 3x3 conv -> d_out fp32
  k_conv3<1><<<dim3(1024), 256, 0, stream>>>(xcl, apo, out_b, (void*)out);
}